// Round 7
// baseline (409.734 us; speedup 1.0000x reference)
//
#include <hip/hip_runtime.h>
#include <stdint.h>

typedef unsigned short u16;
typedef unsigned int u32;

#define B_ 16
#define V_ 16
#define M_ 32
#define L_ 24
#define D_ 128
#define G_ 384   // 3*D
#define N_ 256   // B*V
#define NM_ 8192 // B*V*M
#define OUT_ 193

using bf16x8 = __attribute__((ext_vector_type(8))) __bf16;
using floatx4 = __attribute__((ext_vector_type(4))) float;
using u16x4 = __attribute__((ext_vector_type(4))) u16;

__device__ __forceinline__ float bf2f(u16 u) {
  u32 x = ((u32)u) << 16;
  return __builtin_bit_cast(float, x);
}
__device__ __forceinline__ u16 f2bf(float f) {
  u32 u = __builtin_bit_cast(u32, f);
  u = (u + 0x7FFFu + ((u >> 16) & 1u)) >> 16;
  return (u16)u;
}
__device__ __forceinline__ float sigm_(float x) {
  return __builtin_amdgcn_rcpf(1.0f + __expf(-x));
}
__device__ __forceinline__ float tanh_(float x) {
  float e = __expf(2.0f * x);
  return 1.0f - 2.0f * __builtin_amdgcn_rcpf(e + 1.0f);
}
__device__ __forceinline__ floatx4 mfma16(bf16x8 a, bf16x8 b, floatx4 c) {
  return __builtin_amdgcn_mfma_f32_16x16x32_bf16(a, b, c, 0, 0, 0);
}
// LDS-only barrier: drains lgkmcnt but leaves global loads (vmcnt) in flight.
__device__ __forceinline__ void lds_barrier() {
  asm volatile("s_waitcnt lgkmcnt(0)\n\ts_barrier" ::: "memory");
}

// split a float4 into rounded-hi bf16 + rounded-remainder bf16, vector stores
__device__ __forceinline__ void split4(floatx4 v, u16* __restrict__ hip, u16* __restrict__ lop) {
  u16x4 h, l;
#pragma unroll
  for (int k = 0; k < 4; k++) {
    u16 hb = f2bf(v[k]);
    h[k] = hb;
    l[k] = f2bf(v[k] - bf2f(hb));
  }
  *(u16x4*)hip = h;
  *(u16x4*)lop = l;
}

#define CONVB 1152  // 2*12*G*D / (256*4)
#define VEB 32      // visit-embed blocks (8 visits each, float4 lanes)
#define PEB 1024    // pair-embed blocks (8 rows each, float4 lanes)

// ---------------- Stage 1: weight conv + visit embed + pair embed (fused, float4) ----------------
__global__ __launch_bounds__(256) void k_stage1(
    const int* __restrict__ tc, const int* __restrict__ tp, const int* __restrict__ td,
    const int* __restrict__ tli, const int* __restrict__ tlv,
    const int* __restrict__ tii, const int* __restrict__ tiv,
    const float* __restrict__ ec, const float* __restrict__ ep, const float* __restrict__ ed,
    const float* __restrict__ eli, const float* __restrict__ elv,
    const float* __restrict__ eii, const float* __restrict__ eiv,
    const float* __restrict__ wv, const float* __restrict__ av,
    const float* __restrict__ iw, const float* __restrict__ ib,
    const float* __restrict__ mwih, const float* __restrict__ vwih,
    const float* __restrict__ mwhh, const float* __restrict__ vwhh,
    u16* __restrict__ wih_hi, u16* __restrict__ whh_hi,
    u16* __restrict__ ce_hi, u16* __restrict__ ce_lo,
    u16* __restrict__ vx_hi, u16* __restrict__ vx_lo,
    u16* __restrict__ mx_hi, u16* __restrict__ mx_lo) {
  int blk = blockIdx.x, tid = threadIdx.x;
  if (blk < CONVB) {
    const int SW = 12 * G_ * D_, S5 = 5 * G_ * D_;  // both divisible by 4
    int i4 = (blk * 256 + tid) * 4;
    floatx4 v;
    u16* dst;
    if (i4 < SW) {
      v = *(const floatx4*)(i4 < S5 ? mwih + i4 : vwih + (i4 - S5));
      dst = wih_hi + i4;
    } else {
      int o = i4 - SW;
      v = *(const floatx4*)(o < S5 ? mwhh + o : vwhh + (o - S5));
      dst = whh_hi + o;
    }
    u16x4 h;
#pragma unroll
    for (int k = 0; k < 4; k++) h[k] = f2bf(v[k]);
    *(u16x4*)dst = h;
  } else if (blk < CONVB + VEB) {
    int n = (blk - CONVB) * 8 + (tid >> 5);
    int j = tid & 31;  // float4 column index: d = 4j..4j+3
    floatx4 a0 = {0.f, 0.f, 0.f, 0.f}, a1 = a0, a2 = a0;
#pragma unroll 4
    for (int l = 0; l < L_; l++) {
      a0 += *(const floatx4*)(ec + (size_t)tc[n * L_ + l] * D_ + j * 4);
      a1 += *(const floatx4*)(ep + (size_t)tp[n * L_ + l] * D_ + j * 4);
      a2 += *(const floatx4*)(ed + (size_t)td[n * L_ + l] * D_ + j * 4);
    }
    size_t o0 = (size_t)n * D_ + j * 4;
    split4(a0, ce_hi + o0, ce_lo + o0);
    split4(a1, ce_hi + (size_t)N_ * D_ + o0, ce_lo + (size_t)N_ * D_ + o0);
    split4(a2, ce_hi + (size_t)2 * N_ * D_ + o0, ce_lo + (size_t)2 * N_ * D_ + o0);
    float wq = wv[n], aq = av[n];
    floatx4 iw0 = *(const floatx4*)(iw + j * 4);
    floatx4 iw1 = *(const floatx4*)(iw + D_ + j * 4);
    floatx4 ib0 = *(const floatx4*)(ib + j * 4);
    floatx4 ib1 = *(const floatx4*)(ib + D_ + j * 4);
    floatx4 v1 = wq * iw0 + ib0;
    floatx4 v2 = aq * iw1 + ib1;
    split4(v1, vx_hi + (size_t)5 * N_ * D_ + o0, vx_lo + (size_t)5 * N_ * D_ + o0);
    split4(v2, vx_hi + (size_t)6 * N_ * D_ + o0, vx_lo + (size_t)6 * N_ * D_ + o0);
  } else {
    int r = (blk - CONVB - VEB) * 8 + (tid >> 5);
    int j = tid & 31;
    floatx4 al4 = {0.f, 0.f, 0.f, 0.f}, ai4 = al4;
#pragma unroll 4
    for (int l = 0; l < L_; l++) {
      al4 += *(const floatx4*)(eli + (size_t)tli[r * L_ + l] * D_ + j * 4) *
             *(const floatx4*)(elv + (size_t)tlv[r * L_ + l] * D_ + j * 4);
      ai4 += *(const floatx4*)(eii + (size_t)tii[r * L_ + l] * D_ + j * 4) *
             *(const floatx4*)(eiv + (size_t)tiv[r * L_ + l] * D_ + j * 4);
    }
    size_t o = (size_t)r * D_ + j * 4;
    split4(al4, mx_hi + o, mx_lo + o);
    split4(ai4, mx_hi + (size_t)NM_ * D_ + o, mx_lo + (size_t)NM_ * D_ + o);
  }
}

// ---------------- GRU recurrence, fused input GEMM, depth-2 register double-buffer ----------------
// 8 waves; wave w owns gate-cols dA in [16w,16w+16). Step t (consuming buffer X = A/B by parity):
//  1. issue ds_reads of h(t-1) fragments (latency hidden under x-MFMAs)
//  2. accx = x(t) @ wih^T + bih from REGISTER buffer X, hi/lo as two parallel 4-deep chains
//  3. reload X with x(t+2) via plain global loads -> ~2 steps of slack, compiler emits a
//     counted vmcnt (never a drain). Named A/B buffers force true double-buffering (R6's
//     single-named-buffer was serialized by the compiler to save 32 VGPRs).
//  4. acch = h(t-1) @ whh^T + bhh, hi/lo split chains
//  5. gates, h2, write h hi/lo LDS planes (XOR swizzle), lgkmcnt-only barrier
// MODE 0 keys<3: x constant -> accx once before the loop.
template <int MODE, int TT>
__global__ __launch_bounds__(512, 1) void k_gru8(
    int cpk,
    const u16* __restrict__ xa_hi, const u16* __restrict__ xa_lo,
    const u16* __restrict__ xb_hi, const u16* __restrict__ xb_lo,
    const u16* __restrict__ wih_all, const float* __restrict__ bih_all,
    const u16* __restrict__ whh_all, const float* __restrict__ bhh_all,
    u16* __restrict__ out_hi, u16* __restrict__ out_lo, float* __restrict__ out_f32) {
  int key = blockIdx.x / cpk;
  int chunk = blockIdx.x - key * cpk;
  int n0 = chunk * 16;
  const u16* whh = whh_all + (size_t)key * (G_ * D_);
  const u16* wih = wih_all + (size_t)key * (G_ * D_);

  __shared__ __align__(16) u16 hls[2][2][16 * 128];

  int tid = threadIdx.x;
  int w = tid >> 6, lane = tid & 63, mq = lane & 15, q = lane >> 4;
  int dA = (w << 4) + mq;

  const bool constx = (MODE == 0) && (key < 3);
  const u16 *xhb, *xlb;
  size_t xbase, TS;
  if (MODE == 0) {
    if (key < 3) { xhb = xa_hi; xlb = xa_lo; xbase = ((size_t)key * N_ + n0 + mq) * D_; TS = 0; }
    else { xhb = xb_hi; xlb = xb_lo; xbase = ((size_t)(key - 3) * NM_ + (size_t)(n0 + mq) * M_) * D_; TS = D_; }
  } else {
    xhb = xa_hi; xlb = xa_lo; xbase = ((size_t)key * N_ + mq * 16) * D_; TS = D_;
  }

  // persistent weight fragments
  bf16x8 bw[3][4], wf[3][4];
#pragma unroll
  for (int g = 0; g < 3; g++)
#pragma unroll
    for (int kk = 0; kk < 4; kk++) {
      size_t ro = (size_t)(g * 128 + dA) * D_ + kk * 32 + q * 8;
      bw[g][kk] = *(const bf16x8*)(whh + ro);
      wf[g][kk] = *(const bf16x8*)(wih + ro);
    }
  floatx4 bseed[3], bxs[3];
#pragma unroll
  for (int g = 0; g < 3; g++) {
    float bh = bhh_all[key * G_ + g * 128 + dA];
    float bi = bih_all[key * G_ + g * 128 + dA];
    bseed[g] = {bh, bh, bh, bh};
    bxs[g] = {bi, bi, bi, bi};
  }
  const floatx4 fzero = {0.f, 0.f, 0.f, 0.f};

  // x double buffer: A = even t, B = odd t
  bf16x8 xhA[4], xlA[4], xhB[4], xlB[4];
#pragma unroll
  for (int kk = 0; kk < 4; kk++) {
    xhA[kk] = *(const bf16x8*)(xhb + xbase + kk * 32 + q * 8);
    xlA[kk] = *(const bf16x8*)(xlb + xbase + kk * 32 + q * 8);
  }
  if (!constx) {
#pragma unroll
    for (int kk = 0; kk < 4; kk++) {
      xhB[kk] = *(const bf16x8*)(xhb + xbase + TS + kk * 32 + q * 8);
      xlB[kk] = *(const bf16x8*)(xlb + xbase + TS + kk * 32 + q * 8);
    }
  }

  floatx4 accx[3];
  if (constx) {
#pragma unroll
    for (int g = 0; g < 3; g++) {
      floatx4 axh = mfma16(xhA[0], wf[g][0], bxs[g]);
      axh = mfma16(xhA[1], wf[g][1], axh);
      axh = mfma16(xhA[2], wf[g][2], axh);
      axh = mfma16(xhA[3], wf[g][3], axh);
      floatx4 axl = mfma16(xlA[0], wf[g][0], fzero);
      axl = mfma16(xlA[1], wf[g][1], axl);
      axl = mfma16(xlA[2], wf[g][2], axl);
      axl = mfma16(xlA[3], wf[g][3], axl);
      accx[g] = axh + axl;
    }
  }

  float h_old[4];
#pragma unroll
  for (int k = 0; k < 4; k++) h_old[k] = 0.f;

#define GRU_STEP(T, XH, XL)                                                                \
  {                                                                                        \
    const int t = (T);                                                                     \
    bf16x8 ah[4], al[4];                                                                   \
    if (t > 0) { /* issue h ds_reads first; latency hides under x-MFMAs */                 \
      const u16* hp0 = &hls[(t - 1) & 1][0][0];                                            \
      const u16* hp1 = &hls[(t - 1) & 1][1][0];                                            \
      _Pragma("unroll") for (int kk = 0; kk < 4; kk++) {                                   \
        int off = mq * 128 + (((kk * 4 + q) ^ mq) * 8);                                    \
        ah[kk] = *(const bf16x8*)(hp0 + off);                                              \
        al[kk] = *(const bf16x8*)(hp1 + off);                                              \
      }                                                                                    \
    }                                                                                      \
    if (!constx) {                                                                         \
      _Pragma("unroll") for (int g = 0; g < 3; g++) {                                      \
        floatx4 axh = mfma16(XH[0], wf[g][0], bxs[g]);                                     \
        axh = mfma16(XH[1], wf[g][1], axh);                                                \
        axh = mfma16(XH[2], wf[g][2], axh);                                                \
        axh = mfma16(XH[3], wf[g][3], axh);                                                \
        floatx4 axl = mfma16(XL[0], wf[g][0], fzero);                                      \
        axl = mfma16(XL[1], wf[g][1], axl);                                                \
        axl = mfma16(XL[2], wf[g][2], axl);                                                \
        axl = mfma16(XL[3], wf[g][3], axl);                                                \
        accx[g] = axh + axl;                                                               \
      }                                                                                    \
      if (t + 2 < TT) { /* reload this buffer for t+2: ~2 steps of slack */                \
        size_t xo = xbase + (size_t)(t + 2) * TS;                                          \
        _Pragma("unroll") for (int kk = 0; kk < 4; kk++) {                                 \
          XH[kk] = *(const bf16x8*)(xhb + xo + kk * 32 + q * 8);                           \
          XL[kk] = *(const bf16x8*)(xlb + xo + kk * 32 + q * 8);                           \
        }                                                                                  \
      }                                                                                    \
    }                                                                                      \
    floatx4 acch[3];                                                                       \
    if (t > 0) {                                                                           \
      _Pragma("unroll") for (int g = 0; g < 3; g++) {                                      \
        floatx4 hhi = mfma16(ah[0], bw[g][0], bseed[g]);                                   \
        hhi = mfma16(ah[1], bw[g][1], hhi);                                                \
        hhi = mfma16(ah[2], bw[g][2], hhi);                                                \
        hhi = mfma16(ah[3], bw[g][3], hhi);                                                \
        floatx4 hlo = mfma16(al[0], bw[g][0], fzero);                                      \
        hlo = mfma16(al[1], bw[g][1], hlo);                                                \
        hlo = mfma16(al[2], bw[g][2], hlo);                                                \
        hlo = mfma16(al[3], bw[g][3], hlo);                                                \
        acch[g] = hhi + hlo;                                                               \
      }                                                                                    \
    } else {                                                                               \
      _Pragma("unroll") for (int g = 0; g < 3; g++) acch[g] = bseed[g];                    \
    }                                                                                      \
    u16* wrh = &hls[t & 1][0][0];                                                          \
    u16* wrl = &hls[t & 1][1][0];                                                          \
    _Pragma("unroll") for (int i = 0; i < 4; i++) {                                        \
      int row = q * 4 + i;                                                                 \
      float r = sigm_(accx[0][i] + acch[0][i]);                                            \
      float z = sigm_(accx[1][i] + acch[1][i]);                                            \
      float nn = tanh_(accx[2][i] + r * acch[2][i]);                                       \
      float h2 = (1.0f - z) * nn + z * h_old[i];                                           \
      h_old[i] = h2;                                                                       \
      u32 ub = __builtin_bit_cast(u32, h2);                                                \
      u16 hb = (u16)(ub >> 16);                                                            \
      float rem = h2 - __builtin_bit_cast(float, ub & 0xFFFF0000u);                        \
      u16 lb = f2bf(rem);                                                                  \
      if (t == TT - 1) {                                                                   \
        if (MODE == 0) {                                                                   \
          size_t o = ((size_t)key * N_ + n0 + row) * D_ + dA;                              \
          out_hi[o] = hb;                                                                  \
          out_lo[o] = lb;                                                                  \
        } else {                                                                           \
          out_f32[((size_t)key * 16 + row) * D_ + dA] = h2;                                \
        }                                                                                  \
      } else {                                                                             \
        int idx = row * 128 + (((dA >> 3) ^ row) * 8) + (dA & 7);                          \
        wrh[idx] = hb;                                                                     \
        wrl[idx] = lb;                                                                     \
      }                                                                                    \
    }                                                                                      \
    if (t + 1 < TT) lds_barrier();                                                         \
  }

#pragma unroll 1
  for (int tb = 0; tb < TT; tb += 2) {
    GRU_STEP(tb, xhA, xlA)
    GRU_STEP(tb + 1, xhB, xlB)
  }
#undef GRU_STEP
}

// ---------------- ReLU + FC (parallel GEMV) ----------------
__global__ __launch_bounds__(256) void k_fc(
    const float* __restrict__ vis_h, const float* __restrict__ fc_w,
    const float* __restrict__ fc_b, float* __restrict__ out) {
  int b = blockIdx.x;
  int cg = blockIdx.y;
  int tid = threadIdx.x;
  int j = tid & 15, s = tid >> 4;
  int c = cg * 16 + j;
  bool cv = c < OUT_;

  __shared__ float hbuf[7 * D_];
  __shared__ float red[16][16];
  for (int i = tid; i < 7 * D_; i += 256) {
    float v = vis_h[((size_t)(i >> 7) * 16 + b) * D_ + (i & 127)];
    hbuf[i] = v > 0.f ? v : 0.f;
  }
  __syncthreads();

  float acc = 0.f;
  if (cv) {
    const float* wp = fc_w + (size_t)(s * 56) * OUT_ + c;
#pragma unroll 8
    for (int k = 0; k < 56; k++) acc += hbuf[s * 56 + k] * wp[(size_t)k * OUT_];
  }
  red[s][j] = acc;
  __syncthreads();
  if (s == 0 && cv) {
    float t = 0.f;
#pragma unroll
    for (int m = 0; m < 16; m++) t += red[m][j];
    out[(size_t)b * OUT_ + c] = t + fc_b[c];
  }
}

extern "C" void kernel_launch(void* const* d_in, const int* in_sizes, int n_in,
                              void* d_out, int out_size, void* d_ws, size_t ws_size,
                              hipStream_t stream) {
  (void)in_sizes; (void)n_in; (void)out_size; (void)ws_size;
  const int* tok_cond = (const int*)d_in[0];
  const int* tok_proc = (const int*)d_in[1];
  const int* tok_drug = (const int*)d_in[2];
  const int* tok_lab_item = (const int*)d_in[3];
  const int* tok_lab_value = (const int*)d_in[4];
  const int* tok_inj_item = (const int*)d_in[5];
  const int* tok_inj_value = (const int*)d_in[6];
  const float* weight = (const float*)d_in[7];
  const float* age = (const float*)d_in[8];
  const float* emb_cond = (const float*)d_in[9];
  const float* emb_proc = (const float*)d_in[10];
  const float* emb_drug = (const float*)d_in[11];
  const float* emb_lab_item = (const float*)d_in[12];
  const float* emb_lab_value = (const float*)d_in[13];
  const float* emb_inj_item = (const float*)d_in[14];
  const float* emb_inj_value = (const float*)d_in[15];
  const float* mgru_wih = (const float*)d_in[16];
  const float* mgru_whh = (const float*)d_in[17];
  const float* mgru_bih = (const float*)d_in[18];
  const float* mgru_bhh = (const float*)d_in[19];
  const float* vgru_wih = (const float*)d_in[20];
  const float* vgru_whh = (const float*)d_in[21];
  const float* vgru_bih = (const float*)d_in[22];
  const float* vgru_bhh = (const float*)d_in[23];
  const float* info_w = (const float*)d_in[24];
  const float* info_b = (const float*)d_in[25];
  const float* fc_w = (const float*)d_in[26];
  const float* fc_b = (const float*)d_in[27];

  char* p = (char*)d_ws;
  auto take = [&](size_t bytes) { char* r = p; p += (bytes + 255) & ~(size_t)255; return r; };
  u16* mx_hi = (u16*)take((size_t)2 * NM_ * D_ * 2);
  u16* mx_lo = (u16*)take((size_t)2 * NM_ * D_ * 2);
  u16* ce_hi = (u16*)take((size_t)3 * N_ * D_ * 2);
  u16* ce_lo = (u16*)take((size_t)3 * N_ * D_ * 2);
  u16* vx_hi = (u16*)take((size_t)7 * N_ * D_ * 2);
  u16* vx_lo = (u16*)take((size_t)7 * N_ * D_ * 2);
  float* vis_h = (float*)take((size_t)7 * 16 * D_ * 4);
  u16* wih_hi = (u16*)take((size_t)12 * G_ * D_ * 2);
  u16* whh_hi = (u16*)take((size_t)12 * G_ * D_ * 2);

  k_stage1<<<CONVB + VEB + PEB, 256, 0, stream>>>(
      tok_cond, tok_proc, tok_drug, tok_lab_item, tok_lab_value, tok_inj_item, tok_inj_value,
      emb_cond, emb_proc, emb_drug, emb_lab_item, emb_lab_value, emb_inj_item, emb_inj_value,
      weight, age, info_w, info_b, mgru_wih, vgru_wih, mgru_whh, vgru_whh,
      wih_hi, whh_hi, ce_hi, ce_lo, vx_hi, vx_lo, mx_hi, mx_lo);
  // monitor recurrence (fused input GEMM, depth-2 reg double-buffer): 5 keys x 16 chunks, T=32
  k_gru8<0, 32><<<80, 512, 0, stream>>>(16, ce_hi, ce_lo, mx_hi, mx_lo,
                                        wih_hi, mgru_bih, whh_hi, mgru_bhh,
                                        vx_hi, vx_lo, nullptr);
  // visit recurrence (fused input GEMM, depth-2 reg double-buffer): 7 keys, T=16 -> vis_h f32
  k_gru8<1, 16><<<7, 512, 0, stream>>>(1, vx_hi, vx_lo, nullptr, nullptr,
                                       wih_hi + (size_t)5 * G_ * D_, vgru_bih,
                                       whh_hi + (size_t)5 * G_ * D_, vgru_bhh,
                                       nullptr, nullptr, vis_h);
  k_fc<<<dim3(B_, 13), 256, 0, stream>>>(vis_h, fc_w, fc_b, (float*)d_out);
}

// Round 8
// 216.552 us; speedup vs baseline: 1.8921x; 1.8921x over previous
//
#include <hip/hip_runtime.h>
#include <stdint.h>

typedef unsigned short u16;
typedef unsigned int u32;

#define B_ 16
#define V_ 16
#define M_ 32
#define L_ 24
#define D_ 128
#define G_ 384   // 3*D
#define N_ 256   // B*V
#define NM_ 8192 // B*V*M
#define OUT_ 193

using bf16x8 = __attribute__((ext_vector_type(8))) __bf16;
using floatx4 = __attribute__((ext_vector_type(4))) float;
using u16x4 = __attribute__((ext_vector_type(4))) u16;

__device__ __forceinline__ float bf2f(u16 u) {
  u32 x = ((u32)u) << 16;
  return __builtin_bit_cast(float, x);
}
__device__ __forceinline__ u16 f2bf(float f) {
  u32 u = __builtin_bit_cast(u32, f);
  u = (u + 0x7FFFu + ((u >> 16) & 1u)) >> 16;
  return (u16)u;
}
__device__ __forceinline__ float sigm_(float x) {
  return __builtin_amdgcn_rcpf(1.0f + __expf(-x));
}
__device__ __forceinline__ float tanh_(float x) {
  float e = __expf(2.0f * x);
  return 1.0f - 2.0f * __builtin_amdgcn_rcpf(e + 1.0f);
}
__device__ __forceinline__ floatx4 mfma16(bf16x8 a, bf16x8 b, floatx4 c) {
  return __builtin_amdgcn_mfma_f32_16x16x32_bf16(a, b, c, 0, 0, 0);
}
// LDS-only barrier: drains lgkmcnt but leaves global loads (vmcnt) in flight.
__device__ __forceinline__ void lds_barrier() {
  asm volatile("s_waitcnt lgkmcnt(0)\n\ts_barrier" ::: "memory");
}

// split a float4 into rounded-hi bf16 + rounded-remainder bf16, vector stores
__device__ __forceinline__ void split4(floatx4 v, u16* __restrict__ hip, u16* __restrict__ lop) {
  u16x4 h, l;
#pragma unroll
  for (int k = 0; k < 4; k++) {
    u16 hb = f2bf(v[k]);
    h[k] = hb;
    l[k] = f2bf(v[k] - bf2f(hb));
  }
  *(u16x4*)hip = h;
  *(u16x4*)lop = l;
}

#define CONVB 1152  // 2*12*G*D / (256*4)
#define VEB 32      // visit-embed blocks (8 visits each, float4 lanes)
#define PEB 1024    // pair-embed blocks (8 rows each, float4 lanes)

// ---------------- Stage 1: weight conv + visit embed + pair embed (fused, float4) ----------------
__global__ __launch_bounds__(256) void k_stage1(
    const int* __restrict__ tc, const int* __restrict__ tp, const int* __restrict__ td,
    const int* __restrict__ tli, const int* __restrict__ tlv,
    const int* __restrict__ tii, const int* __restrict__ tiv,
    const float* __restrict__ ec, const float* __restrict__ ep, const float* __restrict__ ed,
    const float* __restrict__ eli, const float* __restrict__ elv,
    const float* __restrict__ eii, const float* __restrict__ eiv,
    const float* __restrict__ wv, const float* __restrict__ av,
    const float* __restrict__ iw, const float* __restrict__ ib,
    const float* __restrict__ mwih, const float* __restrict__ vwih,
    const float* __restrict__ mwhh, const float* __restrict__ vwhh,
    u16* __restrict__ wih_hi, u16* __restrict__ whh_hi,
    u16* __restrict__ ce_hi, u16* __restrict__ ce_lo,
    u16* __restrict__ vx_hi, u16* __restrict__ vx_lo,
    u16* __restrict__ mx_hi, u16* __restrict__ mx_lo) {
  int blk = blockIdx.x, tid = threadIdx.x;
  if (blk < CONVB) {
    const int SW = 12 * G_ * D_, S5 = 5 * G_ * D_;  // both divisible by 4
    int i4 = (blk * 256 + tid) * 4;
    floatx4 v;
    u16* dst;
    if (i4 < SW) {
      v = *(const floatx4*)(i4 < S5 ? mwih + i4 : vwih + (i4 - S5));
      dst = wih_hi + i4;
    } else {
      int o = i4 - SW;
      v = *(const floatx4*)(o < S5 ? mwhh + o : vwhh + (o - S5));
      dst = whh_hi + o;
    }
    u16x4 h;
#pragma unroll
    for (int k = 0; k < 4; k++) h[k] = f2bf(v[k]);
    *(u16x4*)dst = h;
  } else if (blk < CONVB + VEB) {
    int n = (blk - CONVB) * 8 + (tid >> 5);
    int j = tid & 31;  // float4 column index: d = 4j..4j+3
    floatx4 a0 = {0.f, 0.f, 0.f, 0.f}, a1 = a0, a2 = a0;
#pragma unroll 4
    for (int l = 0; l < L_; l++) {
      a0 += *(const floatx4*)(ec + (size_t)tc[n * L_ + l] * D_ + j * 4);
      a1 += *(const floatx4*)(ep + (size_t)tp[n * L_ + l] * D_ + j * 4);
      a2 += *(const floatx4*)(ed + (size_t)td[n * L_ + l] * D_ + j * 4);
    }
    size_t o0 = (size_t)n * D_ + j * 4;
    split4(a0, ce_hi + o0, ce_lo + o0);
    split4(a1, ce_hi + (size_t)N_ * D_ + o0, ce_lo + (size_t)N_ * D_ + o0);
    split4(a2, ce_hi + (size_t)2 * N_ * D_ + o0, ce_lo + (size_t)2 * N_ * D_ + o0);
    float wq = wv[n], aq = av[n];
    floatx4 iw0 = *(const floatx4*)(iw + j * 4);
    floatx4 iw1 = *(const floatx4*)(iw + D_ + j * 4);
    floatx4 ib0 = *(const floatx4*)(ib + j * 4);
    floatx4 ib1 = *(const floatx4*)(ib + D_ + j * 4);
    floatx4 v1 = wq * iw0 + ib0;
    floatx4 v2 = aq * iw1 + ib1;
    split4(v1, vx_hi + (size_t)5 * N_ * D_ + o0, vx_lo + (size_t)5 * N_ * D_ + o0);
    split4(v2, vx_hi + (size_t)6 * N_ * D_ + o0, vx_lo + (size_t)6 * N_ * D_ + o0);
  } else {
    int r = (blk - CONVB - VEB) * 8 + (tid >> 5);
    int j = tid & 31;
    floatx4 al4 = {0.f, 0.f, 0.f, 0.f}, ai4 = al4;
#pragma unroll 4
    for (int l = 0; l < L_; l++) {
      al4 += *(const floatx4*)(eli + (size_t)tli[r * L_ + l] * D_ + j * 4) *
             *(const floatx4*)(elv + (size_t)tlv[r * L_ + l] * D_ + j * 4);
      ai4 += *(const floatx4*)(eii + (size_t)tii[r * L_ + l] * D_ + j * 4) *
             *(const floatx4*)(eiv + (size_t)tiv[r * L_ + l] * D_ + j * 4);
    }
    size_t o = (size_t)r * D_ + j * 4;
    split4(al4, mx_hi + o, mx_lo + o);
    split4(ai4, mx_hi + (size_t)NM_ * D_ + o, mx_lo + (size_t)NM_ * D_ + o);
  }
}

// ---------------- xg = A @ W^T + bias, merged monitor+const launch ----------------
// bid < 1024: monitor keys 3,4 (rows = NM_); bid >= 1024: const keys 0..2 (rows = N_)
__global__ __launch_bounds__(256) void k_gemm_all(
    const u16* __restrict__ mx_hi, const u16* __restrict__ mx_lo,
    const u16* __restrict__ ce_hi, const u16* __restrict__ ce_lo,
    const u16* __restrict__ wih_hi, const float* __restrict__ mbih,
    float* __restrict__ xg_mon, float* __restrict__ xg_c) {
  int bid = blockIdx.x;
  int w = threadIdx.x >> 6, lane = threadIdx.x & 63;
  int mq = lane & 15, q = lane >> 4;
  const u16 *Ahb, *Alb, *Wk;
  const float* bias;
  float* out;
  int row, cb;
  if (bid < 1024) {
    int key = bid >> 9, rem = bid & 511;
    row = (rem >> 2) * 64 + w * 16;
    cb = (rem & 3) * 96;
    Ahb = mx_hi + (size_t)key * NM_ * D_;
    Alb = mx_lo + (size_t)key * NM_ * D_;
    Wk = wih_hi + (size_t)(3 + key) * G_ * D_;
    bias = mbih + (3 + key) * G_;
    out = xg_mon + (size_t)key * NM_ * G_;
  } else {
    int b2 = bid - 1024;
    int key = b2 >> 4, rem = b2 & 15;
    row = (rem >> 2) * 64 + w * 16;
    cb = (rem & 3) * 96;
    Ahb = ce_hi + (size_t)key * N_ * D_;
    Alb = ce_lo + (size_t)key * N_ * D_;
    Wk = wih_hi + (size_t)key * G_ * D_;
    bias = mbih + key * G_;
    out = xg_c + (size_t)key * N_ * G_;
  }

  bf16x8 wf[6][4];
#pragma unroll
  for (int j = 0; j < 6; j++)
#pragma unroll
    for (int kk = 0; kk < 4; kk++)
      wf[j][kk] = *(const bf16x8*)(Wk + (size_t)(cb + j * 16 + mq) * D_ + kk * 32 + q * 8);

  const u16* Ah = Ahb + (size_t)(row + mq) * D_;
  const u16* Al = Alb + (size_t)(row + mq) * D_;
  bf16x8 ah[4], al[4];
#pragma unroll
  for (int kk = 0; kk < 4; kk++) {
    ah[kk] = *(const bf16x8*)(Ah + kk * 32 + q * 8);
    al[kk] = *(const bf16x8*)(Al + kk * 32 + q * 8);
  }

  floatx4 acc[6];
#pragma unroll
  for (int j = 0; j < 6; j++) {
    float bv = bias[cb + j * 16 + mq];
    acc[j] = {bv, bv, bv, bv};
  }
#pragma unroll
  for (int j = 0; j < 6; j++)
#pragma unroll
    for (int kk = 0; kk < 4; kk++) {
      acc[j] = mfma16(ah[kk], wf[j][kk], acc[j]);
      acc[j] = mfma16(al[kk], wf[j][kk], acc[j]);
    }

  float* op = out + (size_t)(row + q * 4) * G_ + cb + mq;
#pragma unroll
  for (int j = 0; j < 6; j++)
#pragma unroll
    for (int i = 0; i < 4; i++) op[(size_t)i * G_ + j * 16] = acc[j][i];
}

// ---------------- visit xg = A @ W^T + bias (tiled: wave = 16 rows x 96 cols) ----------------
__global__ __launch_bounds__(256) void k_gemm_xg(
    const u16* __restrict__ A_hi, const u16* __restrict__ A_lo,
    const u16* __restrict__ W_hi,
    const float* __restrict__ bias,
    float* __restrict__ out, int A_ks, int W_ks, int b_ks, int o_ks) {
  int key = blockIdx.z;
  int w = threadIdx.x >> 6, lane = threadIdx.x & 63;
  int mq = lane & 15, q = lane >> 4;
  int row = blockIdx.x * 64 + w * 16;
  int cb = blockIdx.y * 96;

  const u16* Wk = W_hi + (size_t)key * W_ks;
  bf16x8 wf[6][4];
#pragma unroll
  for (int j = 0; j < 6; j++)
#pragma unroll
    for (int kk = 0; kk < 4; kk++)
      wf[j][kk] = *(const bf16x8*)(Wk + (size_t)(cb + j * 16 + mq) * D_ + kk * 32 + q * 8);

  const u16* Ah = A_hi + (size_t)key * A_ks + (size_t)(row + mq) * D_;
  const u16* Al = A_lo + (size_t)key * A_ks + (size_t)(row + mq) * D_;
  bf16x8 ah[4], al[4];
#pragma unroll
  for (int kk = 0; kk < 4; kk++) {
    ah[kk] = *(const bf16x8*)(Ah + kk * 32 + q * 8);
    al[kk] = *(const bf16x8*)(Al + kk * 32 + q * 8);
  }

  floatx4 acc[6];
#pragma unroll
  for (int j = 0; j < 6; j++) {
    float bv = bias[key * b_ks + cb + j * 16 + mq];
    acc[j] = {bv, bv, bv, bv};
  }
#pragma unroll
  for (int j = 0; j < 6; j++)
#pragma unroll
    for (int kk = 0; kk < 4; kk++) {
      acc[j] = mfma16(ah[kk], wf[j][kk], acc[j]);
      acc[j] = mfma16(al[kk], wf[j][kk], acc[j]);
    }

  float* op = out + (size_t)key * o_ks + (size_t)(row + q * 4) * G_ + cb + mq;
#pragma unroll
  for (int j = 0; j < 6; j++)
#pragma unroll
    for (int i = 0; i < 4; i++) op[(size_t)i * G_ + j * 16] = acc[j][i];
}

// ---------------- GRU recurrence: 8 waves, wave w owns gate-cols d in [16w,16w+16) ----------------
// Per wave: 3 col-tiles (one per gate r/z/n) -> 24 MFMAs/step, 12 xg f32 loads/step,
// 4 gate elements/lane. xg already holds x*wih + bih; h-chains seeded with bhh.
// h state: hi/lo bf16 LDS planes, fragment order, 16B-unit XOR swizzle, ping-pong.
template <int MODE, int TT>
__global__ __launch_bounds__(512, 1) void k_gru8(
    int cpk, const float* __restrict__ xg_a, const float* __restrict__ xg_b,
    const u16* __restrict__ whh_all, const float* __restrict__ bhh_all,
    u16* __restrict__ out_hi, u16* __restrict__ out_lo, float* __restrict__ out_f32) {
  int key = blockIdx.x / cpk;
  int chunk = blockIdx.x % cpk;
  int n0 = chunk * 16;
  const u16* whh = whh_all + (size_t)key * (G_ * D_);
  const float* bhh = bhh_all + (size_t)key * G_;

  __shared__ u16 hls[2][2][16 * 128];

  int tid = threadIdx.x;
  int w = tid >> 6, lane = tid & 63, mq = lane & 15, q = lane >> 4;
  int dA = (w << 4) + mq;

  // whh fragments: tile g covers cols g*128 + dA
  bf16x8 bw[3][4];
#pragma unroll
  for (int g = 0; g < 3; g++)
#pragma unroll
    for (int kk = 0; kk < 4; kk++)
      bw[g][kk] = *(const bf16x8*)(whh + (size_t)(g * 128 + dA) * D_ + kk * 32 + q * 8);

  floatx4 bseed[3];
#pragma unroll
  for (int g = 0; g < 3; g++) {
    float b = bhh[g * 128 + dA];
    bseed[g] = {b, b, b, b};
  }

  const float* xbase;
  size_t RS, TS;
  if (MODE == 0) {
    if (key < 3) { xbase = xg_a + ((size_t)key * N_ + n0) * G_; RS = G_; TS = 0; }
    else { xbase = xg_b + ((size_t)(key - 3) * NM_ + (size_t)n0 * M_) * G_; RS = (size_t)M_ * G_; TS = G_; }
  } else {
    xbase = xg_a + (size_t)key * N_ * G_; RS = (size_t)16 * G_; TS = G_;
  }
  const float* rowp[4];
#pragma unroll
  for (int i = 0; i < 4; i++) rowp[i] = xbase + (size_t)(q * 4 + i) * RS + dA;

  // 4 statically-indexed xg streams; stream P holds time t with t%4==P (depth-3 prefetch).
  float xs[4][12];
#pragma unroll
  for (int s = 0; s < 3; s++) {
    int ts = s < TT ? s : TT - 1;
#pragma unroll
    for (int i = 0; i < 4; i++)
#pragma unroll
      for (int g = 0; g < 3; g++)
        xs[s][i * 3 + g] = rowp[i][(size_t)ts * TS + g * 128];
  }

  float h_old[4];
#pragma unroll
  for (int k = 0; k < 4; k++) h_old[k] = 0.f;

#define GRU_STEP(P)                                                                        \
  {                                                                                        \
    int t = tb + (P);                                                                      \
    {                                                                                      \
      int tpf = t + 3 < TT ? t + 3 : TT - 1;                                               \
      size_t to = (size_t)tpf * TS;                                                        \
      _Pragma("unroll") for (int i = 0; i < 4; i++)                                        \
          _Pragma("unroll") for (int g = 0; g < 3; g++)                                    \
              xs[((P) + 3) & 3][i * 3 + g] = rowp[i][to + g * 128];                        \
    }                                                                                      \
    floatx4 acc[3];                                                                        \
    if (t > 0) {                                                                           \
      const u16* hp0 = &hls[(t - 1) & 1][0][0];                                            \
      const u16* hp1 = &hls[(t - 1) & 1][1][0];                                            \
      bf16x8 ah[4], al[4];                                                                 \
      _Pragma("unroll") for (int kk = 0; kk < 4; kk++) {                                   \
        int off = mq * 128 + (((kk * 4 + q) ^ mq) * 8);                                    \
        ah[kk] = *(const bf16x8*)(hp0 + off);                                              \
        al[kk] = *(const bf16x8*)(hp1 + off);                                              \
      }                                                                                    \
      _Pragma("unroll") for (int g = 0; g < 3; g++) {                                      \
        floatx4 a = mfma16(ah[0], bw[g][0], bseed[g]);                                     \
        a = mfma16(al[0], bw[g][0], a);                                                    \
        a = mfma16(ah[1], bw[g][1], a);                                                    \
        a = mfma16(al[1], bw[g][1], a);                                                    \
        a = mfma16(ah[2], bw[g][2], a);                                                    \
        a = mfma16(al[2], bw[g][2], a);                                                    \
        a = mfma16(ah[3], bw[g][3], a);                                                    \
        acc[g] = mfma16(al[3], bw[g][3], a);                                               \
      }                                                                                    \
    } else {                                                                               \
      _Pragma("unroll") for (int g = 0; g < 3; g++) acc[g] = bseed[g];                     \
    }                                                                                      \
    u16* wrh = &hls[t & 1][0][0];                                                          \
    u16* wrl = &hls[t & 1][1][0];                                                          \
    _Pragma("unroll") for (int i = 0; i < 4; i++) {                                        \
      int row = q * 4 + i;                                                                 \
      float r = sigm_(xs[P][i * 3 + 0] + acc[0][i]);                                       \
      float z = sigm_(xs[P][i * 3 + 1] + acc[1][i]);                                       \
      float nn = tanh_(xs[P][i * 3 + 2] + r * acc[2][i]);                                  \
      float h2 = (1.0f - z) * nn + z * h_old[i];                                           \
      h_old[i] = h2;                                                                       \
      u32 ub = __builtin_bit_cast(u32, h2);                                                \
      u16 hb = (u16)(ub >> 16);                                                            \
      float rem = h2 - __builtin_bit_cast(float, ub & 0xFFFF0000u);                        \
      u16 lb = f2bf(rem);                                                                  \
      if (t == TT - 1) {                                                                   \
        if (MODE == 0) {                                                                   \
          size_t o = ((size_t)key * N_ + n0 + row) * D_ + dA;                              \
          out_hi[o] = hb;                                                                  \
          out_lo[o] = lb;                                                                  \
        } else {                                                                           \
          out_f32[((size_t)key * 16 + row) * D_ + dA] = h2;                                \
        }                                                                                  \
      } else {                                                                             \
        int idx = row * 128 + (((dA >> 3) ^ row) * 8) + (dA & 7);                          \
        wrh[idx] = hb;                                                                     \
        wrl[idx] = lb;                                                                     \
      }                                                                                    \
    }                                                                                      \
    if (t + 1 < TT) lds_barrier();                                                         \
  }

#pragma unroll 1
  for (int tb = 0; tb < TT; tb += 4) {
    GRU_STEP(0)
    GRU_STEP(1)
    GRU_STEP(2)
    GRU_STEP(3)
  }
#undef GRU_STEP
}

// ---------------- ReLU + FC (parallel GEMV) ----------------
__global__ __launch_bounds__(256) void k_fc(
    const float* __restrict__ vis_h, const float* __restrict__ fc_w,
    const float* __restrict__ fc_b, float* __restrict__ out) {
  int b = blockIdx.x;
  int cg = blockIdx.y;
  int tid = threadIdx.x;
  int j = tid & 15, s = tid >> 4;
  int c = cg * 16 + j;
  bool cv = c < OUT_;

  __shared__ float hbuf[7 * D_];
  __shared__ float red[16][16];
  for (int i = tid; i < 7 * D_; i += 256) {
    float v = vis_h[((size_t)(i >> 7) * 16 + b) * D_ + (i & 127)];
    hbuf[i] = v > 0.f ? v : 0.f;
  }
  __syncthreads();

  float acc = 0.f;
  if (cv) {
    const float* wp = fc_w + (size_t)(s * 56) * OUT_ + c;
#pragma unroll 8
    for (int k = 0; k < 56; k++) acc += hbuf[s * 56 + k] * wp[(size_t)k * OUT_];
  }
  red[s][j] = acc;
  __syncthreads();
  if (s == 0 && cv) {
    float t = 0.f;
#pragma unroll
    for (int m = 0; m < 16; m++) t += red[m][j];
    out[(size_t)b * OUT_ + c] = t + fc_b[c];
  }
}

extern "C" void kernel_launch(void* const* d_in, const int* in_sizes, int n_in,
                              void* d_out, int out_size, void* d_ws, size_t ws_size,
                              hipStream_t stream) {
  (void)in_sizes; (void)n_in; (void)out_size; (void)ws_size;
  const int* tok_cond = (const int*)d_in[0];
  const int* tok_proc = (const int*)d_in[1];
  const int* tok_drug = (const int*)d_in[2];
  const int* tok_lab_item = (const int*)d_in[3];
  const int* tok_lab_value = (const int*)d_in[4];
  const int* tok_inj_item = (const int*)d_in[5];
  const int* tok_inj_value = (const int*)d_in[6];
  const float* weight = (const float*)d_in[7];
  const float* age = (const float*)d_in[8];
  const float* emb_cond = (const float*)d_in[9];
  const float* emb_proc = (const float*)d_in[10];
  const float* emb_drug = (const float*)d_in[11];
  const float* emb_lab_item = (const float*)d_in[12];
  const float* emb_lab_value = (const float*)d_in[13];
  const float* emb_inj_item = (const float*)d_in[14];
  const float* emb_inj_value = (const float*)d_in[15];
  const float* mgru_wih = (const float*)d_in[16];
  const float* mgru_whh = (const float*)d_in[17];
  const float* mgru_bih = (const float*)d_in[18];
  const float* mgru_bhh = (const float*)d_in[19];
  const float* vgru_wih = (const float*)d_in[20];
  const float* vgru_whh = (const float*)d_in[21];
  const float* vgru_bih = (const float*)d_in[22];
  const float* vgru_bhh = (const float*)d_in[23];
  const float* info_w = (const float*)d_in[24];
  const float* info_b = (const float*)d_in[25];
  const float* fc_w = (const float*)d_in[26];
  const float* fc_b = (const float*)d_in[27];

  char* p = (char*)d_ws;
  auto take = [&](size_t bytes) { char* r = p; p += (bytes + 255) & ~(size_t)255; return r; };
  u16* mx_hi = (u16*)take((size_t)2 * NM_ * D_ * 2);
  u16* mx_lo = (u16*)take((size_t)2 * NM_ * D_ * 2);
  u16* ce_hi = (u16*)take((size_t)3 * N_ * D_ * 2);
  u16* ce_lo = (u16*)take((size_t)3 * N_ * D_ * 2);
  u16* vx_hi = (u16*)take((size_t)7 * N_ * D_ * 2);
  u16* vx_lo = (u16*)take((size_t)7 * N_ * D_ * 2);
  float* xg_mon = (float*)take((size_t)2 * NM_ * G_ * 4);
  float* xg_c = (float*)take((size_t)3 * N_ * G_ * 4);
  float* xg_v = (float*)take((size_t)7 * N_ * G_ * 4);
  float* vis_h = (float*)take((size_t)7 * 16 * D_ * 4);
  u16* wih_hi = (u16*)take((size_t)12 * G_ * D_ * 2);
  u16* whh_hi = (u16*)take((size_t)12 * G_ * D_ * 2);

  k_stage1<<<CONVB + VEB + PEB, 256, 0, stream>>>(
      tok_cond, tok_proc, tok_drug, tok_lab_item, tok_lab_value, tok_inj_item, tok_inj_value,
      emb_cond, emb_proc, emb_drug, emb_lab_item, emb_lab_value, emb_inj_item, emb_inj_value,
      weight, age, info_w, info_b, mgru_wih, vgru_wih, mgru_whh, vgru_whh,
      wih_hi, whh_hi, ce_hi, ce_lo, vx_hi, vx_lo, mx_hi, mx_lo);
  // xg for monitor keys 3,4 (8192 rows each) + const keys 0..2 (256 rows each), one launch
  k_gemm_all<<<1024 + 48, 256, 0, stream>>>(
      mx_hi, mx_lo, ce_hi, ce_lo, wih_hi, mgru_bih, xg_mon, xg_c);
  // monitor recurrence: 5 keys x 16 chunks, T=32 -> writes vx keys 0..4
  k_gru8<0, 32><<<80, 512, 0, stream>>>(16, xg_c, xg_mon, whh_hi, mgru_bhh,
                                        vx_hi, vx_lo, nullptr);
  // xg for visit keys (0..6): rows = 256 each
  k_gemm_xg<<<dim3(N_ / 64, 4, 7), 256, 0, stream>>>(
      vx_hi, vx_lo, wih_hi + (size_t)5 * G_ * D_,
      vgru_bih, xg_v, N_ * D_, G_ * D_, G_, N_ * G_);
  // visit recurrence: 7 keys, T=16 -> vis_h f32
  k_gru8<1, 16><<<7, 512, 0, stream>>>(1, xg_v, nullptr, whh_hi + (size_t)5 * G_ * D_, vgru_bhh,
                                       nullptr, nullptr, vis_h);
  k_fc<<<dim3(B_, 13), 256, 0, stream>>>(vis_h, fc_w, fc_b, (float*)d_out);
}